// Round 9
// baseline (444.350 us; speedup 1.0000x reference)
//
#include <hip/hip_runtime.h>
#include <hip/hip_bf16.h>

#define N_NODES 100000
#define E_EDGES 1600000
#define ETOT    1700000   // E + N self-loops
#define NB_SCAN 391       // ceil(N/256)
#define F_IN    128
#define HC      64
#define OUT_C   40
#define NEG_SLOPE 0.2f
#define BN_EPS  1e-5f

// destination banding for CSR build: 8 bands (col window 0.85 MB + cursor
// 50 KB per band -> single-XCD L2-resident) + nt edge reads (R8 lesson: the
// streaming reads must not evict the dirty col lines).
#define BAND_SZ 12500
#define N_BAND  8
#define SLICE_E 8192      // edges per block-slice
#define N_SLICE 196       // ceil(E_EDGES / SLICE_E)

// fp32 param block layout (element offsets)
#define P_W1   0
#define P_AS1  8192
#define P_AD1  8256
#define P_B1   8320
#define P_BNG  8384
#define P_BNB  8448
#define P_BNM  8512
#define P_BNV  8576
#define P_W2   8640
#define P_AS2  12736
#define P_AD2  12800
#define P_B2   12864
#define P_WF   12928
#define P_BF   15488
#define P_TOT  15528

typedef __attribute__((ext_vector_type(8))) short short8;
typedef __attribute__((ext_vector_type(4))) float floatx4;

__device__ __forceinline__ unsigned short f2bf(float f) {   // RNE fp32->bf16
    unsigned int u = __float_as_uint(f);
    unsigned int r = u + 0x7FFFu + ((u >> 16) & 1u);
    return (unsigned short)(r >> 16);
}
__device__ __forceinline__ float bf2f(unsigned short u) {
    return __uint_as_float(((unsigned int)u) << 16);
}

// ---------------- dtype detection ----------------
__global__ __launch_bounds__(64) void detect_kernel(const unsigned short* __restrict__ x,
                                                    int* __restrict__ flag) {
    int t = threadIdx.x;
    bool huge = false;
#pragma unroll
    for (int i = 0; i < 4; ++i) {
        unsigned short u = x[(t * 4 + i) * 2];
        float v = __uint_as_float(((unsigned int)u) << 16);
        if (!(fabsf(v) < 1e4f)) huge = true;
    }
    unsigned long long b = __ballot(huge);
    if (t == 0) *flag = (b != 0ull) ? 1 : 0;             // 1 => fp32 tensors
}

// ---------------- small-param conversion to fp32 ----------------
struct CvtArgs { const void* ptr[14]; int len[14]; };

__global__ __launch_bounds__(256) void cvt_params_kernel(CvtArgs a,
                                                         const int* __restrict__ flag,
                                                         float* __restrict__ dst) {
    int f = *flag;
    int i = blockIdx.x * 256 + threadIdx.x;
    if (i >= P_TOT) return;
    int k = 0, off = 0;
    while (i >= off + a.len[k]) { off += a.len[k]; ++k; }
    int j = i - off;
    float v = f ? ((const float*)a.ptr[k])[j]
                : __bfloat162float(((const __hip_bfloat16*)a.ptr[k])[j]);
    dst[i] = v;
}

// ---------------- W1/W2 -> bf16 MFMA B-fragment order; + folded BN consts ----------------
// kbn[c] = gamma*rsqrt(var+eps); kbn[64+c] = (b1[c]-mean)*kbn[c] + beta
__global__ __launch_bounds__(256) void build_frags_kernel(const float* __restrict__ prm,
                                                          unsigned short* __restrict__ fw1,
                                                          unsigned short* __restrict__ fw2,
                                                          float* __restrict__ kbn) {
    int i = blockIdx.x * 256 + threadIdx.x;
    if (i < 8192) {
        int j = i & 7, l = (i >> 3) & 63, q = (i >> 9) & 3, t = i >> 11;
        int k = q * 32 + (l >> 4) * 8 + j;
        int n = t * 16 + (l & 15);
        fw1[i] = f2bf(prm[P_W1 + k * 64 + n]);
    } else if (i < 12288) {
        int f = i - 8192;
        int j = f & 7, l = (f >> 3) & 63, q = (f >> 9) & 1, t = f >> 10;
        int k = q * 32 + (l >> 4) * 8 + j;
        int n = t * 16 + (l & 15);
        fw2[f] = f2bf(prm[P_W2 + k * 64 + n]);
    } else if (i < 12352) {
        int c = i - 12288;
        float scale = prm[P_BNG + c] * rsqrtf(prm[P_BNV + c] + BN_EPS);
        kbn[c]      = scale;
        kbn[64 + c] = (prm[P_B1 + c] - prm[P_BNM + c]) * scale + prm[P_BNB + c];
    }
}

// ---------------- CSR build: banded histogram, nt edge reads ----------------
__global__ __launch_bounds__(256) void hist_kernel(const int* __restrict__ ei,
                                                   int* __restrict__ deg) {
    int band  = blockIdx.x & (N_BAND - 1);
    int slice = blockIdx.x / N_BAND;
    int blo = band * BAND_SZ, bhi = blo + BAND_SZ;
    const unsigned long long* dst2 = (const unsigned long long*)(ei + E_EDGES);
    int base4 = slice * (SLICE_E / 4);
#pragma unroll
    for (int it = 0; it < 8; ++it) {
        int i4 = base4 + it * 256 + threadIdx.x;
        if (i4 < E_EDGES / 4) {
            unsigned long long p0 = __builtin_nontemporal_load(&dst2[i4 * 2]);
            unsigned long long p1 = __builtin_nontemporal_load(&dst2[i4 * 2 + 1]);
            int d[4] = {(int)(p0 & 0xFFFFFFFFull), (int)(p0 >> 32),
                        (int)(p1 & 0xFFFFFFFFull), (int)(p1 >> 32)};
#pragma unroll
            for (int c = 0; c < 4; ++c)
                if (d[c] >= blo && d[c] < bhi) atomicAdd(&deg[d[c]], 1);
        }
    }
}

// parallel scan; degree counted as deg[i]+1 (self-loop folded in)
__global__ __launch_bounds__(256) void scanA_kernel(const int* __restrict__ deg,
                                                    int* __restrict__ bsum) {
    __shared__ int sm[256];
    int t = threadIdx.x;
    int i = blockIdx.x * 256 + t;
    sm[t] = (i < N_NODES) ? deg[i] + 1 : 0;
    __syncthreads();
    for (int off = 128; off > 0; off >>= 1) {
        if (t < off) sm[t] += sm[t + off];
        __syncthreads();
    }
    if (t == 0) bsum[blockIdx.x] = sm[0];
}

__global__ __launch_bounds__(512) void scanB_kernel(const int* __restrict__ bsum,
                                                    int* __restrict__ boff,
                                                    int* __restrict__ row_start) {
    __shared__ int sm[512];
    int t = threadIdx.x;
    int v = (t < NB_SCAN) ? bsum[t] : 0;
    sm[t] = v;
    __syncthreads();
    for (int off = 1; off < 512; off <<= 1) {
        int o = (t >= off) ? sm[t - off] : 0;
        __syncthreads();
        sm[t] += o;
        __syncthreads();
    }
    if (t < NB_SCAN) boff[t] = sm[t] - v;
    if (t == NB_SCAN - 1) row_start[N_NODES] = sm[t];   // == ETOT
}

__global__ __launch_bounds__(256) void scanC_kernel(const int* __restrict__ deg,
                                                    const int* __restrict__ boff,
                                                    int* __restrict__ row_start,
                                                    int* __restrict__ cursor,
                                                    int* __restrict__ col) {
    __shared__ int sm[256];
    int t = threadIdx.x;
    int i = blockIdx.x * 256 + t;
    int v = (i < N_NODES) ? deg[i] + 1 : 0;
    sm[t] = v;
    __syncthreads();
    for (int off = 1; off < 256; off <<= 1) {
        int o = (t >= off) ? sm[t - off] : 0;
        __syncthreads();
        sm[t] += o;
        __syncthreads();
    }
    if (i < N_NODES) {
        int excl = sm[t] - v + boff[blockIdx.x];
        row_start[i] = excl;
        cursor[i]    = excl + 1;   // slot 0 = self-loop
        col[excl]    = i;
    }
}

// ---------------- banded scatter, nt edge reads ----------------
__global__ __launch_bounds__(256) void scatter_kernel(const int* __restrict__ ei,
                                                      int* __restrict__ cursor,
                                                      int* __restrict__ col) {
    int band  = blockIdx.x & (N_BAND - 1);
    int slice = blockIdx.x / N_BAND;
    int blo = band * BAND_SZ, bhi = blo + BAND_SZ;
    const unsigned long long* dst2 = (const unsigned long long*)(ei + E_EDGES);
    int base4 = slice * (SLICE_E / 4);
#pragma unroll
    for (int it = 0; it < 8; ++it) {
        int i4 = base4 + it * 256 + threadIdx.x;
        if (i4 < E_EDGES / 4) {
            unsigned long long p0 = __builtin_nontemporal_load(&dst2[i4 * 2]);
            unsigned long long p1 = __builtin_nontemporal_load(&dst2[i4 * 2 + 1]);
            int d[4] = {(int)(p0 & 0xFFFFFFFFull), (int)(p0 >> 32),
                        (int)(p1 & 0xFFFFFFFFull), (int)(p1 >> 32)};
#pragma unroll
            for (int c = 0; c < 4; ++c) {
                if (d[c] >= blo && d[c] < bhi) {
                    int s = __builtin_nontemporal_load(ei + i4 * 4 + c);
                    int pos = atomicAdd(&cursor[d[c]], 1);
                    col[pos] = s;
                }
            }
        }
    }
}

__device__ __forceinline__ float leaky(float v) { return v > 0.f ? v : NEG_SLOPE * v; }

__device__ __forceinline__ float red64(float v) {
#pragma unroll
    for (int off = 32; off > 0; off >>= 1) v += __shfl_xor(v, off, 64);
    return v;
}
__device__ __forceinline__ float red16(float v) {
#pragma unroll
    for (int off = 8; off > 0; off >>= 1) v += __shfl_xor(v, off, 64);
    return v;
}

// ---------------- MFMA GEMM 1: h_bf[N,64] = x[N,128] @ W1, + fused alpha ----------------
__global__ __launch_bounds__(128) void gemm1_kernel(const void* __restrict__ x,
                                                    const unsigned short* __restrict__ fw1,
                                                    const float* __restrict__ prm,
                                                    const int* __restrict__ flag,
                                                    unsigned short* __restrict__ h_bf,
                                                    float* __restrict__ as_,
                                                    float* __restrict__ ad_) {
    __shared__ short lx[2 * 4 * 64 * 8];   // 8 KB
    int t = threadIdx.x;
    int f = *flag;
    int base = blockIdx.x * 32;

#pragma unroll
    for (int i = 0; i < 4; ++i) {
        int cid = i * 128 + t;
        int m = cid >> 4, c = cid & 15;
        int q = c >> 2, g = c & 3;
        int loff = (((m >> 4) * 4 + q) * 64 + g * 16 + (m & 15)) * 8;
        short8 s;
        if (f) {
            const float4* p = (const float4*)((const float*)x + ((size_t)(base + m) << 7) + (c << 3));
            float4 u0 = p[0], u1 = p[1];
            s[0] = (short)f2bf(u0.x); s[1] = (short)f2bf(u0.y);
            s[2] = (short)f2bf(u0.z); s[3] = (short)f2bf(u0.w);
            s[4] = (short)f2bf(u1.x); s[5] = (short)f2bf(u1.y);
            s[6] = (short)f2bf(u1.z); s[7] = (short)f2bf(u1.w);
        } else {
            s = *(const short8*)((const unsigned short*)x + ((size_t)(base + m) << 7) + (c << 3));
        }
        *(short8*)&lx[loff] = s;
    }
    __syncthreads();

    int w = t >> 6, lane = t & 63;
    short8 a[4];
#pragma unroll
    for (int q = 0; q < 4; ++q) a[q] = *(short8*)&lx[((w * 4 + q) * 64 + lane) * 8];

    const short8* bw = (const short8*)fw1;
    floatx4 acc[4];
#pragma unroll
    for (int tt = 0; tt < 4; ++tt) acc[tt] = (floatx4){0.f, 0.f, 0.f, 0.f};
#pragma unroll
    for (int tt = 0; tt < 4; ++tt) {
#pragma unroll
        for (int q = 0; q < 4; ++q) {
            short8 b = bw[(tt * 4 + q) * 64 + lane];
            acc[tt] = __builtin_amdgcn_mfma_f32_16x16x32_bf16(a[q], b, acc[tt], 0, 0, 0);
        }
    }

    int cl = lane & 15, grp = lane >> 4;
#pragma unroll
    for (int tt = 0; tt < 4; ++tt) {
#pragma unroll
        for (int r = 0; r < 4; ++r) {
            int node = base + w * 16 + grp * 4 + r;
            h_bf[(size_t)node * 64 + tt * 16 + cl] = f2bf(acc[tt][r]);
        }
    }

    float as0 = prm[P_AS1 + 0  + cl], as1 = prm[P_AS1 + 16 + cl],
          as2 = prm[P_AS1 + 32 + cl], as3 = prm[P_AS1 + 48 + cl];
    float ad0 = prm[P_AD1 + 0  + cl], ad1 = prm[P_AD1 + 16 + cl],
          ad2 = prm[P_AD1 + 32 + cl], ad3 = prm[P_AD1 + 48 + cl];
#pragma unroll
    for (int r = 0; r < 4; ++r) {
        float sh0 = red16(acc[0][r] * as0 + acc[1][r] * as1);
        float sh1 = red16(acc[2][r] * as2 + acc[3][r] * as3);
        float dh0 = red16(acc[0][r] * ad0 + acc[1][r] * ad1);
        float dh1 = red16(acc[2][r] * ad2 + acc[3][r] * ad3);
        if (cl == 0) {
            int node = base + w * 16 + grp * 4 + r;
            as_[node * 2] = sh0;  as_[node * 2 + 1] = sh1;
            ad_[node * 2] = dh0;  ad_[node * 2 + 1] = dh1;
        }
    }
}

// ---------------- MFMA GEMM 2: h_bf = x1_bf[N,64] @ W2, + fused alpha ----------------
__global__ __launch_bounds__(128) void gemm2_kernel(const unsigned short* __restrict__ x1_bf,
                                                    const unsigned short* __restrict__ fw2,
                                                    const float* __restrict__ prm,
                                                    unsigned short* __restrict__ h_bf,
                                                    float* __restrict__ as_,
                                                    float* __restrict__ ad_) {
    __shared__ short lx[2 * 2 * 64 * 8];   // 4 KB
    int t = threadIdx.x;
    int base = blockIdx.x * 32;

#pragma unroll
    for (int i = 0; i < 2; ++i) {
        int cid = i * 128 + t;
        int m = cid >> 3, c = cid & 7;
        int q = c >> 2, g = c & 3;
        int loff = (((m >> 4) * 2 + q) * 64 + g * 16 + (m & 15)) * 8;
        short8 s = *(const short8*)(x1_bf + ((size_t)(base + m) << 6) + (c << 3));
        *(short8*)&lx[loff] = s;
    }
    __syncthreads();

    int w = t >> 6, lane = t & 63;
    short8 a[2];
#pragma unroll
    for (int q = 0; q < 2; ++q) a[q] = *(short8*)&lx[((w * 2 + q) * 64 + lane) * 8];

    const short8* bw = (const short8*)fw2;
    floatx4 acc[4];
#pragma unroll
    for (int tt = 0; tt < 4; ++tt) acc[tt] = (floatx4){0.f, 0.f, 0.f, 0.f};
#pragma unroll
    for (int tt = 0; tt < 4; ++tt) {
#pragma unroll
        for (int q = 0; q < 2; ++q) {
            short8 b = bw[(tt * 2 + q) * 64 + lane];
            acc[tt] = __builtin_amdgcn_mfma_f32_16x16x32_bf16(a[q], b, acc[tt], 0, 0, 0);
        }
    }

    int cl = lane & 15, grp = lane >> 4;
#pragma unroll
    for (int tt = 0; tt < 4; ++tt) {
#pragma unroll
        for (int r = 0; r < 4; ++r) {
            int node = base + w * 16 + grp * 4 + r;
            h_bf[(size_t)node * 64 + tt * 16 + cl] = f2bf(acc[tt][r]);
        }
    }

    float as0 = prm[P_AS2 + 0  + cl], as1 = prm[P_AS2 + 16 + cl],
          as2 = prm[P_AS2 + 32 + cl], as3 = prm[P_AS2 + 48 + cl];
    float ad0 = prm[P_AD2 + 0  + cl], ad1 = prm[P_AD2 + 16 + cl],
          ad2 = prm[P_AD2 + 32 + cl], ad3 = prm[P_AD2 + 48 + cl];
#pragma unroll
    for (int r = 0; r < 4; ++r) {
        float sh0 = red16(acc[0][r] * as0 + acc[1][r] * as1);
        float sh1 = red16(acc[2][r] * as2 + acc[3][r] * as3);
        float dh0 = red16(acc[0][r] * ad0 + acc[1][r] * ad1);
        float dh1 = red16(acc[2][r] * ad2 + acc[3][r] * ad3);
        if (cl == 0) {
            int node = base + w * 16 + grp * 4 + r;
            as_[node * 2] = sh0;  as_[node * 2 + 1] = sh1;
            ad_[node * 2] = dh0;  ad_[node * 2 + 1] = dh1;
        }
    }
}

// ---------------- aggregation core: 2 nodes per wave ----------------
// Wave handles nodes vp (lanes 0-31) and vp+1 (lanes 32-63). Fast path when
// both degs <= 32: slot = hl&3, cg = hl>>2; one dwordx4 covers 8 channels of
// one edge -> 4 edges/instr/node x 2 nodes. All shuffles convergent; lanes
// beyond deg carry w=0. Result: each lane ends with 2 adjacent channels
// (ch = cg*8 + b0*4 + b1*2), written to LDS res[node][64].
// Slow path (either deg > 32, wave-uniform, ~3e-4 of nodes): generic
// per-edge loop per node, lane = channel.
__device__ __forceinline__ void agg_core2(const unsigned short* __restrict__ h_bf,
                                          const float* __restrict__ as_,
                                          const float* __restrict__ ad_,
                                          const int* __restrict__ row_start,
                                          const int* __restrict__ col,
                                          int vp, int lane, float res[][64], int rbase) {
    int side = lane >> 5, hl = lane & 31;
    int v = vp + side;
    int rs = row_start[v], re = row_start[v + 1];
    int deg = re - rs;
    int dox = __shfl_xor(deg, 32, 64);
    int mx = max(deg, dox);                      // wave-uniform

    if (mx <= 32) {
        float adv0 = ad_[v * 2], adv1 = ad_[v * 2 + 1];
        int sj = 0;
        float w0 = 0.f, w1 = 0.f;
        if (hl < deg) {
            sj = col[rs + hl];
            float2 av = *(const float2*)&as_[sj * 2];
            w0 = __expf(leaky(av.x + adv0));
            w1 = __expf(leaky(av.y + adv1));
        }
        // half-wave denominators (masks 1..16 stay within the 32-half)
        float s0 = w0, s1 = w1;
#pragma unroll
        for (int off = 1; off <= 16; off <<= 1) {
            s0 += __shfl_xor(s0, off, 64);
            s1 += __shfl_xor(s1, off, 64);
        }
        int slot = hl & 3, cg = hl >> 2;
        bool hi = cg >= 4;
        float rdh = 1.f / ((hi ? s1 : s0) + 1e-16f);
        float acc[8] = {0.f,0.f,0.f,0.f,0.f,0.f,0.f,0.f};
        int nit = (mx + 3) >> 2;
        int sbase = side << 5;
        for (int g = 0; g < nit; ++g) {
            int idx = sbase + g * 4 + slot;      // source lane in my half
            int   sA = __shfl(sj, idx, 64);
            float wa = __shfl(w0, idx, 64);
            float wb = __shfl(w1, idx, 64);
            float w  = hi ? wb : wa;             // 0 beyond deg
            uint4 d = *(const uint4*)(h_bf + ((size_t)sA << 6) + (cg << 3));
#pragma unroll
            for (int q = 0; q < 4; ++q) {
                unsigned int dw = (&d.x)[q];
                acc[2 * q]     = fmaf(w, __uint_as_float(dw << 16),          acc[2 * q]);
                acc[2 * q + 1] = fmaf(w, __uint_as_float(dw & 0xFFFF0000u), acc[2 * q + 1]);
            }
        }
        // slot reduction: xor-1 then xor-2, halving register count
        bool b0 = (slot & 1) != 0, b1 = (slot & 2) != 0;
        float t0[4];
#pragma unroll
        for (int q = 0; q < 4; ++q) {
            float send = b0 ? acc[q] : acc[q + 4];
            float recv = __shfl_xor(send, 1, 64);
            t0[q] = (b0 ? acc[q + 4] : acc[q]) + recv;
        }
        float sA0 = b1 ? t0[0] : t0[2];
        float rA0 = __shfl_xor(sA0, 2, 64);
        float r0 = (b1 ? t0[2] : t0[0]) + rA0;
        float sA1 = b1 ? t0[1] : t0[3];
        float rA1 = __shfl_xor(sA1, 2, 64);
        float r1 = (b1 ? t0[3] : t0[1]) + rA1;
        int ch = (cg << 3) + (b0 ? 4 : 0) + (b1 ? 2 : 0);
        float2* dst = (float2*)&res[rbase + side][ch];
        *dst = make_float2(r0 * rdh, r1 * rdh);
    } else {
        // generic: full wave per node, lane = channel
        int headL = lane >> 5;
        for (int s2 = 0; s2 < 2; ++s2) {
            int u = vp + s2;
            int urs = row_start[u], ure = row_start[u + 1];
            float uadv0 = ad_[u * 2], uadv1 = ad_[u * 2 + 1];
            float advh = headL ? uadv1 : uadv0;
            float t0 = 0.f, t1 = 0.f;
            for (int e = urs + lane; e < ure; e += 64) {
                int s = col[e];
                float2 av = *(const float2*)&as_[s * 2];
                t0 += __expf(leaky(av.x + uadv0));
                t1 += __expf(leaky(av.y + uadv1));
            }
            t0 = red64(t0); t1 = red64(t1);
            float rdh = 1.f / ((headL ? t1 : t0) + 1e-16f);
            float a0 = 0.f;
            for (int e = urs; e < ure; ++e) {
                int s = col[e];
                float w = __expf(leaky(as_[s * 2 + headL] + advh));
                a0 = fmaf(w, bf2f(h_bf[(size_t)s * 64 + lane]), a0);
            }
            res[rbase + s2][lane] = a0 * rdh;
        }
    }
}

// ---------------- agg layer 1 (+folded bias/BN, ELU) -> x1_bf ----------------
// block 256 = 4 waves = 8 nodes; grid N/8
__global__ __launch_bounds__(256) void agg1_kernel(const unsigned short* __restrict__ h_bf,
                                                   const float* __restrict__ as_,
                                                   const float* __restrict__ ad_,
                                                   const int* __restrict__ row_start,
                                                   const int* __restrict__ col,
                                                   const float* __restrict__ kbn,
                                                   unsigned short* __restrict__ x1_bf) {
    __shared__ float res[8][64];
    int t = threadIdx.x, wid = t >> 6, lane = t & 63;
    int vp = blockIdx.x * 8 + wid * 2;
    agg_core2(h_bf, as_, ad_, row_start, col, vp, lane, res, wid * 2);

    // epilogue: lane handles channels 2*hl, 2*hl+1 of node vp+side (wave-local,
    // no barrier: same wave wrote res via DS, compiler inserts lgkmcnt)
    int side = lane >> 5, hl = lane & 31;
    int v = vp + side;
    int ch = hl * 2;
    float2 pr = *(float2*)&res[wid * 2 + side][ch];
    float kA0 = kbn[ch],     kB0 = kbn[64 + ch];
    float kA1 = kbn[ch + 1], kB1 = kbn[64 + ch + 1];
    float r0 = fmaf(pr.x, kA0, kB0);
    float r1 = fmaf(pr.y, kA1, kB1);
    r0 = r0 > 0.f ? r0 : expm1f(r0);   // ELU
    r1 = r1 > 0.f ? r1 : expm1f(r1);
    unsigned int packed = (unsigned int)f2bf(r0) | ((unsigned int)f2bf(r1) << 16);
    *(unsigned int*)&x1_bf[(size_t)v * 64 + ch] = packed;
}

// ---------------- agg layer 2 + JK max + fused projection -> out [N,40] ----------------
__global__ __launch_bounds__(256) void agg2_kernel(const unsigned short* __restrict__ h_bf,
                                                   const float* __restrict__ as_,
                                                   const float* __restrict__ ad_,
                                                   const int* __restrict__ row_start,
                                                   const int* __restrict__ col,
                                                   const float* __restrict__ prm,
                                                   const unsigned short* __restrict__ x1_bf,
                                                   const int* __restrict__ flag,
                                                   void* __restrict__ out) {
    __shared__ float res[8][64];
    __shared__ float Wfs[2560];
    int t = threadIdx.x, wid = t >> 6, lane = t & 63;
#pragma unroll
    for (int i = 0; i < 10; ++i) Wfs[i * 256 + t] = prm[P_WF + i * 256 + t];

    int vp = blockIdx.x * 8 + wid * 2;
    agg_core2(h_bf, as_, ad_, row_start, col, vp, lane, res, wid * 2);

    // JK max, in place (wave-local)
    int side = lane >> 5, hl = lane & 31;
    int v = vp + side;
    int ch = hl * 2;
    float2 pr = *(float2*)&res[wid * 2 + side][ch];
    float x20 = pr.x + prm[P_B2 + ch];
    float x21 = pr.y + prm[P_B2 + ch + 1];
    unsigned int xp = *(const unsigned int*)&x1_bf[(size_t)v * 64 + ch];
    float xj0 = fmaxf(bf2f((unsigned short)(xp & 0xFFFF)), x20);
    float xj1 = fmaxf(bf2f((unsigned short)(xp >> 16)),    x21);
    *(float2*)&res[wid * 2 + side][ch] = make_float2(xj0, xj1);
    __syncthreads();

    // projection: 8 nodes x 40 outputs = 320 work items
    for (int idx = t; idx < 320; idx += 256) {
        int n = idx / 40, o = idx - n * 40;
        float po = 0.f;
#pragma unroll
        for (int c = 0; c < 64; c += 4) {
            po = fmaf(res[n][c],     Wfs[c * 40 + o],       po);
            po = fmaf(res[n][c + 1], Wfs[(c + 1) * 40 + o], po);
            po = fmaf(res[n][c + 2], Wfs[(c + 2) * 40 + o], po);
            po = fmaf(res[n][c + 3], Wfs[(c + 3) * 40 + o], po);
        }
        float r = po + prm[P_BF + o];
        size_t oidx = (size_t)(blockIdx.x * 8 + n) * 40 + o;
        if (*flag) ((float*)out)[oidx] = r;
        else ((__hip_bfloat16*)out)[oidx] = __float2bfloat16(r);
    }
}

extern "C" void kernel_launch(void* const* d_in, const int* in_sizes, int n_in,
                              void* d_out, int out_size, void* d_ws, size_t ws_size,
                              hipStream_t stream) {
    (void)in_sizes; (void)n_in; (void)out_size; (void)ws_size;
    const void* node_feat = d_in[0];
    const int*  edge_idx  = (const int*)d_in[1];

    char* ws = (char*)d_ws;
    size_t off = 0;
    auto alloc = [&](size_t bytes) -> void* {
        void* p = ws + off;
        off += (bytes + 255) & ~(size_t)255;
        return p;
    };
    unsigned short* h_bf  = (unsigned short*)alloc((size_t)N_NODES * 64 * 2);  // 12.8 MB
    unsigned short* x1_bf = (unsigned short*)alloc((size_t)N_NODES * 64 * 2);  // 12.8 MB
    float* as_ = (float*)alloc((size_t)N_NODES * 2 * 4);
    float* ad_ = (float*)alloc((size_t)N_NODES * 2 * 4);
    int* deg       = (int*)alloc((size_t)N_NODES * 4);
    int* row_start = (int*)alloc((size_t)(N_NODES + 1) * 4);
    int* cursor    = (int*)alloc((size_t)N_NODES * 4);
    int* col       = (int*)alloc((size_t)ETOT * 4);         // 6.8 MB
    int* bsum      = (int*)alloc((size_t)NB_SCAN * 4);
    int* boff      = (int*)alloc((size_t)NB_SCAN * 4);
    float* prm     = (float*)alloc((size_t)P_TOT * 4);
    unsigned short* fw1 = (unsigned short*)alloc(8192 * 2);
    unsigned short* fw2 = (unsigned short*)alloc(4096 * 2);
    float* kbn     = (float*)alloc(128 * 4);
    int* flag      = (int*)alloc(256);

    detect_kernel<<<1, 64, 0, stream>>>((const unsigned short*)node_feat, flag);
    CvtArgs ca;
    const int lens[14] = {8192, 64, 64, 64, 64, 64, 64, 64, 4096, 64, 64, 64, 2560, 40};
    for (int i = 0; i < 14; ++i) { ca.ptr[i] = d_in[i + 2]; ca.len[i] = lens[i]; }
    cvt_params_kernel<<<(P_TOT + 255) / 256, 256, 0, stream>>>(ca, flag, prm);
    build_frags_kernel<<<49, 256, 0, stream>>>(prm, fw1, fw2, kbn);

    // CSR build: banded hist -> scan (+1 self-loop) -> banded scatter
    hipMemsetAsync(deg, 0, (size_t)N_NODES * 4, stream);
    hist_kernel<<<N_SLICE * N_BAND, 256, 0, stream>>>(edge_idx, deg);
    scanA_kernel<<<NB_SCAN, 256, 0, stream>>>(deg, bsum);
    scanB_kernel<<<1, 512, 0, stream>>>(bsum, boff, row_start);
    scanC_kernel<<<NB_SCAN, 256, 0, stream>>>(deg, boff, row_start, cursor, col);
    scatter_kernel<<<N_SLICE * N_BAND, 256, 0, stream>>>(edge_idx, cursor, col);

    gemm1_kernel<<<N_NODES / 32, 128, 0, stream>>>(node_feat, fw1, prm, flag,
                                                   h_bf, as_, ad_);
    agg1_kernel<<<N_NODES / 8, 256, 0, stream>>>(h_bf, as_, ad_, row_start, col,
                                                 kbn, x1_bf);
    gemm2_kernel<<<N_NODES / 32, 128, 0, stream>>>(x1_bf, fw2, prm,
                                                   h_bf, as_, ad_);
    agg2_kernel<<<N_NODES / 8, 256, 0, stream>>>(h_bf, as_, ad_, row_start, col,
                                                 prm, x1_bf, flag, d_out);
}